// Round 1
// 358.828 us; speedup vs baseline: 1.0227x; 1.0227x over previous
//
#include <hip/hip_runtime.h>

// QuadConv R5: R4 + non-temporal output stores.
//  Theory: qconv is latency-bound (MfmaUtil 21%, HBM 27-42%, occ 20%). FETCH_SIZE
//  326 MB >> 64 MiB feature table => ~50% of the 604 MB gather stream misses LLC
//  and pays ~900cy HBM latency. The 134-170 MB fp32 output stream allocating into
//  Infinity Cache is the eviction suspect. nt-stores on `out` (and nt-loads of the
//  never-reused fp32 source in the convert pass) keep featb LLC-resident.
//  Predict: FETCH 326->~120 MB, MfmaUtil 21->26%, qconv 151->~125 us.
//
//  Carried from R4: barrier-free MFMA GEMM with AITER-style pipelined K-loop.
//  - A (gathered neighbor features, bf16) staged into per-wave-private LDS via
//    global_load_lds, full-cache-line coalesced (8 lanes x 16B per row window),
//    XOR-swizzled so fragment ds_read_b128 is bank-conflict-free.
//  - Manual s_waitcnt(vmcnt) with statically counted issue schedule; no
//    __syncthreads anywhere (no vmcnt(0) drains).
//  - B (packed W fragments) register ring from global, dist-2/ring-3.
//  - M-unroll 2: wave owns rows [wave*32, +32) and +128.

#define NPTS    262144
#define CIN     128
#define COUT    128
#define KNBR    9
#define KDIM    1152
#define NKS     72
#define NFRAGS  288
#define NFRAGS_PAD 296            // +2 t-groups so B(t+2) needs no guard
#define MT      256

typedef __bf16  bf16x8 __attribute__((ext_vector_type(8)));
typedef float   f32x4  __attribute__((ext_vector_type(4)));
typedef float   f32x16 __attribute__((ext_vector_type(16)));

// s_waitcnt imm: vmcnt[3:0]@[3:0], vmcnt[5:4]@[15:14], exp=7, lgkm=15 (no wait)
#define VMCNT(n) (((n) & 0xF) | (((n) >> 4) << 14) | (0xF << 8) | (7 << 4))

// ---- pre-pass 1: features fp32 -> bf16 ----
// fp32 source is read exactly once => nt loads (don't pollute LLC; featb, which
// the gather kernel re-reads 9x, should own the cache). featb store stays cached.
__global__ __launch_bounds__(256) void convert_feat_kernel(const float* __restrict__ f,
                                                           __bf16* __restrict__ fb) {
    size_t i = ((size_t)blockIdx.x * 256 + threadIdx.x) * 8;
    f32x4 a = __builtin_nontemporal_load((const f32x4*)(f + i));
    f32x4 b = __builtin_nontemporal_load((const f32x4*)(f + i + 4));
    bf16x8 o;
#pragma unroll
    for (int k = 0; k < 4; ++k) { o[k] = (__bf16)a[k]; o[k + 4] = (__bf16)b[k]; }
    *(bf16x8*)(fb + i) = o;
}

// ---- pre-pass 2: W -> bf16 MFMA B-fragment order (+ zero rows) ----
__global__ __launch_bounds__(256) void pack_w_kernel(const float* __restrict__ W,
                                                     __bf16* __restrict__ Wp,
                                                     __bf16* __restrict__ zrow_b) {
    if (blockIdx.x == NFRAGS / 4) {
        int t = threadIdx.x;
        if (t < CIN) zrow_b[t] = (__bf16)0.f;
        return;
    }
    int t    = blockIdx.x * 256 + threadIdx.x;
    int lane = t & 63;
    int frag = t >> 6;
    int nt = frag & 3;
    int ks = frag >> 2;
    int n  = nt * 32 + (lane & 31);
    int k0 = ks * 16 + (lane >> 5) * 8;
    const f32x4* src = (const f32x4*)(W + (size_t)n * KDIM + k0);
    f32x4 v0 = src[0], v1 = src[1];
    bf16x8 o;
#pragma unroll
    for (int i = 0; i < 4; ++i) { o[i] = (__bf16)v0[i]; o[i + 4] = (__bf16)v1[i]; }
    *(bf16x8*)(Wp + (size_t)frag * 512 + lane * 8) = o;
}

// ---- main kernel ----
__global__ __launch_bounds__(256, 2) void qconv_kernel(
    const __bf16* __restrict__ featb,  // [NPTS,128] bf16
    const int*    __restrict__ nidx,   // [NPTS,9]
    const __bf16* __restrict__ Wp,     // packed B-fragments (padded)
    const __bf16* __restrict__ zrow,   // 128 bf16 zeros
    const float*  __restrict__ bias,
    float*        __restrict__ out)
{
    // per-wave: 2 bufs x 2 tiles x 4 KB (32 rows x 128 B half-row windows)
    __shared__ __align__(16) char lds_raw[4 * 2 * 2 * 4096];

    const int tid  = threadIdx.x;
    const int lane = tid & 63;
    const int wave = tid >> 6;
    const int l31  = lane & 31;
    const int half = lane >> 5;
    const int rb   = blockIdx.x * MT;
    char* myLds = lds_raw + wave * 16384;

    // staging role: 8 lanes per row, lane covers swizzled 16B chunk of 128B window
    const int srow = lane >> 3;   // row within 8-row group
    const int schk = lane & 7;    // LDS slot; fetches global chunk schk^srow

    // idx base addresses for the 8 staged row-groups (n = T*4 + i)
    const int* ia[8];
#pragma unroll
    for (int n = 0; n < 8; ++n) {
        int rg = rb + (n >> 2) * 128 + wave * 32 + (n & 3) * 8 + srow;
        ia[n] = nidx + (size_t)rg * KNBR;
    }

    f32x16 acc[8];
#pragma unroll
    for (int a = 0; a < 8; ++a)
#pragma unroll
        for (int i = 0; i < 16; ++i) acc[a][i] = 0.f;

    const __bf16* Pst[8];   // row pointers for the j currently being staged
    int NPidx[8];           // raw indices for next j
    bf16x8 Bb[3][4];        // B register ring

    auto convertP = [&](void) {
#pragma unroll
        for (int n = 0; n < 8; ++n)
            Pst[n] = (NPidx[n] >= 0) ? featb + (size_t)NPidx[n] * CIN : zrow;
    };
    // stage chunk c (ks [4c,4c+4)): 8 fire-and-forget 1KB global_load_lds
    auto stage_chunk = [&](int c) {
        const int buf  = c & 1;                  // also the half-row byte sel
        const int eoff = (c & 1) * 64 + (schk ^ srow) * 8;   // bf16 elems
#pragma unroll
        for (int n = 0; n < 8; ++n) {
            const int T = n >> 2, i = n & 3;
            const __bf16* g = Pst[n] + eoff;
            char* dst = myLds + buf * 8192 + T * 4096 + i * 1024;
            __builtin_amdgcn_global_load_lds(
                (const __attribute__((address_space(1))) void*)g,
                (__attribute__((address_space(3))) void*)dst,
                16, 0, 0);
        }
    };
    auto issueB = [&](int t) {
#pragma unroll
        for (int nt = 0; nt < 4; ++nt)
            Bb[t % 3][nt] = *(const bf16x8*)(Wp + (size_t)(t * 4 + nt) * 512 + lane * 8);
    };
    auto readA = [&](int buf, int T, int ksl) -> bf16x8 {
        const int s = (ksl * 2 + half) ^ (l31 & 7);
        return *(const bf16x8*)(myLds + buf * 8192 + T * 4096 + l31 * 128 + s * 16);
    };

    // ---- prologue ----
#pragma unroll
    for (int n = 0; n < 8; ++n) NPidx[n] = ia[n][0];   // j = 0
    convertP();
    __builtin_amdgcn_sched_barrier(0);
    stage_chunk(0);
    __builtin_amdgcn_sched_barrier(0);
    issueB(0); issueB(1);

    // ---- main loop: 9 j's x 2 chunks; fully unrolled for constant vmcnt ----
#pragma unroll
    for (int j = 0; j < KNBR; ++j) {
        // ===== even chunk c = 2j =====
        __builtin_amdgcn_sched_barrier(0);
        if (j == 0) __builtin_amdgcn_s_waitcnt(VMCNT(8));   // after stage(0): B x8
        else        __builtin_amdgcn_s_waitcnt(VMCNT(16));  // after stage(2j): B x16
        __builtin_amdgcn_sched_barrier(0);
        stage_chunk(2 * j + 1);                             // odd chunk, same j
        __builtin_amdgcn_sched_barrier(0);
        {
            const int jn = (j + 1 < KNBR) ? j + 1 : KNBR - 1;
#pragma unroll
            for (int n = 0; n < 8; ++n) NPidx[n] = ia[n][jn];   // 8 vmem
#pragma unroll
            for (int ksl = 0; ksl < 4; ++ksl) {
                const int t = j * 8 + ksl;
                issueB(t + 2);                                   // 4 vmem
                bf16x8 a0 = readA(0, 0, ksl);
                bf16x8 a1 = readA(0, 1, ksl);
#pragma unroll
                for (int nt = 0; nt < 4; ++nt) {
                    acc[nt]     = __builtin_amdgcn_mfma_f32_32x32x16_bf16(a0, Bb[t % 3][nt], acc[nt], 0, 0, 0);
                    acc[4 + nt] = __builtin_amdgcn_mfma_f32_32x32x16_bf16(a1, Bb[t % 3][nt], acc[4 + nt], 0, 0, 0);
                }
            }
        }
        // ===== odd chunk c = 2j+1 =====
        __builtin_amdgcn_sched_barrier(0);
        __builtin_amdgcn_s_waitcnt(VMCNT(24));   // after stage(2j+1): idx x8 + B x16
        __builtin_amdgcn_sched_barrier(0);
        convertP();                              // NPidx ~1 chunk old
        stage_chunk(2 * j + 2);                  // even chunk of next j (j=8: dummy)
        __builtin_amdgcn_sched_barrier(0);
#pragma unroll
        for (int ksl = 4; ksl < 8; ++ksl) {
            const int t = j * 8 + ksl;
            issueB(t + 2);
            bf16x8 a0 = readA(1, 0, ksl - 4);
            bf16x8 a1 = readA(1, 1, ksl - 4);
#pragma unroll
            for (int nt = 0; nt < 4; ++nt) {
                acc[nt]     = __builtin_amdgcn_mfma_f32_32x32x16_bf16(a0, Bb[t % 3][nt], acc[nt], 0, 0, 0);
                acc[4 + nt] = __builtin_amdgcn_mfma_f32_32x32x16_bf16(a1, Bb[t % 3][nt], acc[4 + nt], 0, 0, 0);
            }
        }
    }

    // ---- epilogue: C/D layout col=lane&31, row=(r&3)+8*(r>>2)+4*half ----
    // nt stores: out is write-once, never re-read by this kernel; keep it from
    // allocating in Infinity Cache so the 64 MiB featb gather table stays resident.
#pragma unroll
    for (int nt = 0; nt < 4; ++nt) {
        const int col = nt * 32 + l31;
        const float bv = bias[col];
#pragma unroll
        for (int r = 0; r < 16; ++r) {
            const int row = (r & 3) + 8 * (r >> 2) + 4 * half;
            __builtin_nontemporal_store(acc[nt][r] + bv,
                &out[(size_t)(rb + wave * 32 + row) * COUT + col]);
            __builtin_nontemporal_store(acc[4 + nt][r] + bv,
                &out[(size_t)(rb + 128 + wave * 32 + row) * COUT + col]);
        }
    }
}

// ---- safety fallback (never expected to run; ws_size has been ~>64MiB) ----
__global__ void qconv_naive(const float* __restrict__ feat, const int* __restrict__ nidx,
                            const float* __restrict__ W, const float* __restrict__ bias,
                            float* __restrict__ out) {
    int p = blockIdx.x, c = threadIdx.x;
    float s = bias[c];
    for (int j = 0; j < KNBR; ++j) {
        int g = nidx[(size_t)p * KNBR + j];
        if (g < 0) continue;
        const float* fr = feat + (size_t)g * CIN;
        const float* wr = W + (size_t)c * KDIM + j * CIN;
        for (int k = 0; k < CIN; ++k) s += fr[k] * wr[k];
    }
    out[(size_t)p * COUT + c] = s;
}

extern "C" void kernel_launch(void* const* d_in, const int* in_sizes, int n_in,
                              void* d_out, int out_size, void* d_ws, size_t ws_size,
                              hipStream_t stream) {
    const float* feat = (const float*)d_in[0];
    const int*   nidx = (const int*)d_in[1];
    const float* W    = (const float*)d_in[2];
    const float* bias = (const float*)d_in[3];
    float*       out  = (float*)d_out;

    const size_t FEATB_BYTES = (size_t)NPTS * CIN * 2;        // 64 MiB
    const size_t WP_BYTES    = (size_t)NFRAGS_PAD * 512 * 2;  // 296 KiB

    if (ws_size >= FEATB_BYTES + WP_BYTES + 512) {
        __bf16* featb  = (__bf16*)d_ws;
        __bf16* Wp     = (__bf16*)((char*)d_ws + FEATB_BYTES);
        __bf16* zrow_b = (__bf16*)((char*)d_ws + FEATB_BYTES + WP_BYTES);
        convert_feat_kernel<<<NPTS * CIN / (256 * 8), 256, 0, stream>>>(feat, featb);
        pack_w_kernel<<<NFRAGS / 4 + 1, 256, 0, stream>>>(W, Wp, zrow_b);
        qconv_kernel<<<NPTS / MT, 256, 0, stream>>>(featb, nidx, Wp, zrow_b, bias, out);
    } else {
        qconv_naive<<<NPTS, COUT, 0, stream>>>(feat, nidx, W, bias, out);
    }
}

// Round 4
// 345.214 us; speedup vs baseline: 1.0630x; 1.0394x over previous
//
#include <hip/hip_runtime.h>

// QuadConv R8: distance-2 staging (R7) + VGPR diet + margin-8 vmcnt waits.
//  R7 post-mortem: NaN despite formally-correct vmcnt accounting. Root-cause
//  hypothesis: launch_bounds(256,2) + 128 AGPR acc caps arch-VGPR at 128
//  (R4 reported exactly 128 = zero headroom); R7's restructure pushed pressure
//  over -> scratch spills = extra vmem ops -> manual vmcnt undercounts ->
//  waits release early -> MFMA reads unwritten LDS -> NaN.
//  Fixes:
//   (1) VGPR diet: ia[8] (16 regs) -> 2 base ptrs + const offsets;
//       Pst[8] 64-bit ptrs (16 regs) -> NPoff[8] u32 byte-offsets (zrow lives
//       at constant offset ZOFFB inside the workspace, so the -1-neighbor
//       select is a 32-bit cndmask). ~30 regs freed -> no spills.
//   (2) Margin-8 waits (exact-8): tolerates up to 8 compiler vmem ops per
//       window; verified both in-flight stage groups stay in flight.
//  Theory unchanged (R5/R6): MLP-bound gather; occupancy register-pinned at
//  2 waves/SIMD, so deepen per-wave MLP: stage(c+2) issues right after chunk
//  c's ds_reads drain (lgkmcnt(0)); 16 gathers in flight per wave vs 8.
//  Predict: PASS; qconv 151 -> ~105-125 us, BW 3.4 -> 4.4-5.2 TB/s,
//  FETCH ~325 MB, MfmaUtil 26-30%.
//
//  Exact vmcnt bounds (ops issued after the stage that must retire):
//   even j=0: {st1 8, idx1 8, B0/B1 8}                = 24 -> wait 16
//   even j>0: odd(j-1) {B 16, idx 8, st 8}            = 32 -> wait 24
//   odd  j=0: {idx1 8, B0/B1 8, evenB 16, st2 8}      = 40 -> wait 32
//   odd  j>0: even(j) {B 16, st 8}                    = 24 -> wait 16

#define NPTS    262144
#define CIN     128
#define COUT    128
#define KNBR    9
#define KDIM    1152
#define NFRAGS  288
#define NFRAGS_PAD 296            // +2 t-groups so B(t+2) needs no guard
#define MT      256
// zrow byte offset inside workspace: FEATB_BYTES + WP_BYTES
#define ZOFFB   67411968u         // 64*2^20 + 296*1024

typedef __bf16  bf16x8 __attribute__((ext_vector_type(8)));
typedef float   f32x4  __attribute__((ext_vector_type(4)));
typedef float   f32x16 __attribute__((ext_vector_type(16)));

// s_waitcnt imm: vmcnt[3:0]@[3:0], vmcnt[5:4]@[15:14], exp=7, lgkm=15 (no wait)
#define VMCNT(n) (((n) & 0xF) | (((n) >> 4) << 14) | (0xF << 8) | (7 << 4))
// lgkm=0 (wait all LDS), vmcnt=63 (no wait), exp=7
#define LGKM0    (0xF | (3 << 14) | (7 << 4))

// ---- pre-pass 1: features fp32 -> bf16 (nt loads: fp32 source is read once) ----
__global__ __launch_bounds__(256) void convert_feat_kernel(const float* __restrict__ f,
                                                           __bf16* __restrict__ fb) {
    size_t i = ((size_t)blockIdx.x * 256 + threadIdx.x) * 8;
    f32x4 a = __builtin_nontemporal_load((const f32x4*)(f + i));
    f32x4 b = __builtin_nontemporal_load((const f32x4*)(f + i + 4));
    bf16x8 o;
#pragma unroll
    for (int k = 0; k < 4; ++k) { o[k] = (__bf16)a[k]; o[k + 4] = (__bf16)b[k]; }
    *(bf16x8*)(fb + i) = o;
}

// ---- pre-pass 2: W -> bf16 MFMA B-fragment order (+ zero rows) ----
__global__ __launch_bounds__(256) void pack_w_kernel(const float* __restrict__ W,
                                                     __bf16* __restrict__ Wp,
                                                     __bf16* __restrict__ zrow_b) {
    if (blockIdx.x == NFRAGS / 4) {
        int t = threadIdx.x;
        if (t < CIN) zrow_b[t] = (__bf16)0.f;
        return;
    }
    int t    = blockIdx.x * 256 + threadIdx.x;
    int lane = t & 63;
    int frag = t >> 6;
    int nt = frag & 3;
    int ks = frag >> 2;
    int n  = nt * 32 + (lane & 31);
    int k0 = ks * 16 + (lane >> 5) * 8;
    const f32x4* src = (const f32x4*)(W + (size_t)n * KDIM + k0);
    f32x4 v0 = src[0], v1 = src[1];
    bf16x8 o;
#pragma unroll
    for (int i = 0; i < 4; ++i) { o[i] = (__bf16)v0[i]; o[i + 4] = (__bf16)v1[i]; }
    *(bf16x8*)(Wp + (size_t)frag * 512 + lane * 8) = o;
}

// ---- main kernel ----
__global__ __launch_bounds__(256, 2) void qconv_kernel(
    const __bf16* __restrict__ featb,  // [NPTS,128] bf16 (= workspace base)
    const int*    __restrict__ nidx,   // [NPTS,9]
    const __bf16* __restrict__ Wp,     // packed B-fragments (padded)
    const float*  __restrict__ bias,
    float*        __restrict__ out)
{
    // per-wave: 2 bufs x 2 tiles x 4 KB (32 rows x 128 B half-row windows)
    __shared__ __align__(16) char lds_raw[4 * 2 * 2 * 4096];

    const int tid  = threadIdx.x;
    const int lane = tid & 63;
    const int wave = tid >> 6;
    const int l31  = lane & 31;
    const int half = lane >> 5;
    const int rb   = blockIdx.x * MT;
    char* myLds = lds_raw + wave * 16384;

    // staging role: 8 lanes per row, lane covers swizzled 16B chunk of 128B window
    const int srow = lane >> 3;   // row within 8-row group
    const int schk = lane & 7;    // LDS slot; fetches global chunk schk^srow
    const int sxor = (schk ^ srow) * 16;   // byte offset of fetched global chunk

    // idx bases: row-group n covers rows rb + (n>>2)*128 + wave*32 + (n&3)*8 + srow
    // iab0 holds the n<4 base; n>=4 adds 128 rows (= +1152 int elements).
    const int* iab0 = nidx + (size_t)(rb + wave * 32 + srow) * KNBR;
    const int* iab1 = iab0 + 128 * KNBR;

    f32x16 acc[8];
#pragma unroll
    for (int a = 0; a < 8; ++a)
#pragma unroll
        for (int i = 0; i < 16; ++i) acc[a][i] = 0.f;

    int      NPidx[8];   // raw indices (transient)
    unsigned NPoff[8];   // byte offsets into workspace for rows being staged
    bf16x8 Bb[3][4];     // B register ring

    auto loadIdx = [&](int jn) {
#pragma unroll
        for (int n = 0; n < 8; ++n)
            NPidx[n] = ((n >> 2) ? iab1 : iab0)[(n & 3) * 8 * KNBR + jn];
    };
    auto convertP = [&](void) {
#pragma unroll
        for (int n = 0; n < 8; ++n)
            NPoff[n] = (NPidx[n] >= 0) ? ((unsigned)NPidx[n] << 8) : ZOFFB;
    };
    // stage chunk c (half-row (c&1) of current j): 8 fire-and-forget 1KB DMAs
    auto stage_chunk = [&](int c) {
        const int eoff = (c & 1) * 128 + sxor;   // bytes within the 256-B row
#pragma unroll
        for (int n = 0; n < 8; ++n) {
            const char* g = (const char*)featb + (NPoff[n] + eoff);
            char* dst = myLds + (c & 1) * 8192 + (n >> 2) * 4096 + (n & 3) * 1024;
            __builtin_amdgcn_global_load_lds(
                (const __attribute__((address_space(1))) void*)g,
                (__attribute__((address_space(3))) void*)dst,
                16, 0, 0);
        }
    };
    auto issueB = [&](int t) {
#pragma unroll
        for (int nt = 0; nt < 4; ++nt)
            Bb[t % 3][nt] = *(const bf16x8*)(Wp + (size_t)(t * 4 + nt) * 512 + lane * 8);
    };
    auto readA = [&](int buf, int T, int ksl) -> bf16x8 {
        const int s = (ksl * 2 + half) ^ (l31 & 7);
        return *(const bf16x8*)(myLds + buf * 8192 + T * 4096 + l31 * 128 + s * 16);
    };

    // ---- prologue: issue order pinned = stage0(8) stage1(8) idx1(8) B0(4) B1(4) ----
    loadIdx(0);
    convertP();                                        // (waits idx0; once)
    __builtin_amdgcn_sched_barrier(0);
    stage_chunk(0);
    __builtin_amdgcn_sched_barrier(0);
    stage_chunk(1);
    __builtin_amdgcn_sched_barrier(0);
    loadIdx(1);
    __builtin_amdgcn_sched_barrier(0);
    issueB(0); issueB(1);

    // ---- main loop: 9 j's x 2 chunks, distance-2 staging; fully unrolled ----
#pragma unroll
    for (int j = 0; j < KNBR; ++j) {
        // ===== even chunk c = 2j (buf0) =====
        __builtin_amdgcn_sched_barrier(0);
        if (j == 0) __builtin_amdgcn_s_waitcnt(VMCNT(16));   // exact 24, margin 8
        else        __builtin_amdgcn_s_waitcnt(VMCNT(24));   // exact 32, margin 8
        __builtin_amdgcn_sched_barrier(0);
#pragma unroll
        for (int ksl = 0; ksl < 4; ++ksl) {
            const int t = j * 8 + ksl;
            issueB(t + 2);
            bf16x8 a0 = readA(0, 0, ksl);
            bf16x8 a1 = readA(0, 1, ksl);
            if (ksl == 3) {
                // all 8 ds_reads of buf0 issued; drain them -> buf0 is free,
                // then overwrite it with chunk 2j+2 (j+1's even chunk).
                __builtin_amdgcn_sched_barrier(0);
                __builtin_amdgcn_s_waitcnt(LGKM0);
                __builtin_amdgcn_sched_barrier(0);
                convertP();                    // NPoff <- rows of j+1 (clamped idx)
                stage_chunk(2 * j + 2);        // j=8: dummy (valid mem, unused)
                __builtin_amdgcn_sched_barrier(0);
            }
#pragma unroll
            for (int nt = 0; nt < 4; ++nt) {
                acc[nt]     = __builtin_amdgcn_mfma_f32_32x32x16_bf16(a0, Bb[t % 3][nt], acc[nt], 0, 0, 0);
                acc[4 + nt] = __builtin_amdgcn_mfma_f32_32x32x16_bf16(a1, Bb[t % 3][nt], acc[4 + nt], 0, 0, 0);
            }
        }
        // ===== odd chunk c = 2j+1 (buf1) =====
        __builtin_amdgcn_sched_barrier(0);
        if (j == 0) __builtin_amdgcn_s_waitcnt(VMCNT(32));   // exact 40, margin 8
        else        __builtin_amdgcn_s_waitcnt(VMCNT(16));   // exact 24, margin 8
        __builtin_amdgcn_sched_barrier(0);
#pragma unroll
        for (int ksl = 4; ksl < 8; ++ksl) {
            const int t = j * 8 + ksl;
            issueB(t + 2);
            bf16x8 a0 = readA(1, 0, ksl - 4);
            bf16x8 a1 = readA(1, 1, ksl - 4);
            if (ksl == 7) {
                __builtin_amdgcn_sched_barrier(0);
                __builtin_amdgcn_s_waitcnt(LGKM0);
                __builtin_amdgcn_sched_barrier(0);
                // idx for j+2 (clamped); consumed by convertP at even(j+1)
                loadIdx((j + 2 <= KNBR - 1) ? j + 2 : KNBR - 1);
                stage_chunk(2 * j + 3);        // odd chunk of j+1 (j=8: dummy)
                __builtin_amdgcn_sched_barrier(0);
            }
#pragma unroll
            for (int nt = 0; nt < 4; ++nt) {
                acc[nt]     = __builtin_amdgcn_mfma_f32_32x32x16_bf16(a0, Bb[t % 3][nt], acc[nt], 0, 0, 0);
                acc[4 + nt] = __builtin_amdgcn_mfma_f32_32x32x16_bf16(a1, Bb[t % 3][nt], acc[4 + nt], 0, 0, 0);
            }
        }
    }

    // drain all outstanding vmem (incl. the two dummy tail stages) before the
    // wave can exit and its LDS be re-allocated to another block.
    __builtin_amdgcn_sched_barrier(0);
    __builtin_amdgcn_s_waitcnt(VMCNT(0));
    __builtin_amdgcn_sched_barrier(0);

    // ---- epilogue: C/D layout col=lane&31, row=(r&3)+8*(r>>2)+4*half ----
#pragma unroll
    for (int nt = 0; nt < 4; ++nt) {
        const int col = nt * 32 + l31;
        const float bv = bias[col];
#pragma unroll
        for (int r = 0; r < 16; ++r) {
            const int row = (r & 3) + 8 * (r >> 2) + 4 * half;
            __builtin_nontemporal_store(acc[nt][r] + bv,
                &out[(size_t)(rb + wave * 32 + row) * COUT + col]);
            __builtin_nontemporal_store(acc[4 + nt][r] + bv,
                &out[(size_t)(rb + 128 + wave * 32 + row) * COUT + col]);
        }
    }
}

// ---- safety fallback (never expected to run; ws_size has been ~>64MiB) ----
__global__ void qconv_naive(const float* __restrict__ feat, const int* __restrict__ nidx,
                            const float* __restrict__ W, const float* __restrict__ bias,
                            float* __restrict__ out) {
    int p = blockIdx.x, c = threadIdx.x;
    float s = bias[c];
    for (int j = 0; j < KNBR; ++j) {
        int g = nidx[(size_t)p * KNBR + j];
        if (g < 0) continue;
        const float* fr = feat + (size_t)g * CIN;
        const float* wr = W + (size_t)c * KDIM + j * CIN;
        for (int k = 0; k < CIN; ++k) s += fr[k] * wr[k];
    }
    out[(size_t)p * COUT + c] = s;
}

extern "C" void kernel_launch(void* const* d_in, const int* in_sizes, int n_in,
                              void* d_out, int out_size, void* d_ws, size_t ws_size,
                              hipStream_t stream) {
    const float* feat = (const float*)d_in[0];
    const int*   nidx = (const int*)d_in[1];
    const float* W    = (const float*)d_in[2];
    const float* bias = (const float*)d_in[3];
    float*       out  = (float*)d_out;

    const size_t FEATB_BYTES = (size_t)NPTS * CIN * 2;        // 64 MiB
    const size_t WP_BYTES    = (size_t)NFRAGS_PAD * 512 * 2;  // 296 KiB
    // NOTE: zrow sits at d_ws + FEATB_BYTES + WP_BYTES == d_ws + ZOFFB (kernel
    // addresses it as featb-base + ZOFFB; keep these in sync).

    if (ws_size >= FEATB_BYTES + WP_BYTES + 512) {
        __bf16* featb  = (__bf16*)d_ws;
        __bf16* Wp     = (__bf16*)((char*)d_ws + FEATB_BYTES);
        __bf16* zrow_b = (__bf16*)((char*)d_ws + FEATB_BYTES + WP_BYTES);
        convert_feat_kernel<<<NPTS * CIN / (256 * 8), 256, 0, stream>>>(feat, featb);
        pack_w_kernel<<<NFRAGS / 4 + 1, 256, 0, stream>>>(W, Wp, zrow_b);
        qconv_kernel<<<NPTS / MT, 256, 0, stream>>>(featb, nidx, Wp, bias, out);
    } else {
        qconv_naive<<<NPTS, COUT, 0, stream>>>(feat, nidx, W, bias, out);
    }
}